// Round 6
// baseline (338.396 us; speedup 1.0000x reference)
//
#include <hip/hip_runtime.h>
#include <hip/hip_bf16.h>

#define T_STEPS 512
#define BATCH 32
#define NST 64
#define DIM 1024
#define LOG2E 1.44269504f

typedef _Float16 f16x8 __attribute__((ext_vector_type(8)));
typedef _Float16 f16x4 __attribute__((ext_vector_type(4)));
typedef _Float16 f16x2 __attribute__((ext_vector_type(2)));
typedef float f32x4 __attribute__((ext_vector_type(4)));

// ---------------- W concat + fp16 convert ----------------
// Wc[256][1024] fp16, row order [Wk | Wq | Wv | Wa].
__global__ __launch_bounds__(256) void wconv(
    const float* __restrict__ Wk, const float* __restrict__ Wv,
    const float* __restrict__ Wq, const float* __restrict__ Wa,
    _Float16* __restrict__ Wc) {
  const int n = blockIdx.x;
  const int g = n >> 6, r = n & 63;
  const float* W = (g == 0) ? Wk : (g == 1) ? Wq : (g == 2) ? Wv : Wa;
  float4 v = *(const float4*)(W + (size_t)r * DIM + threadIdx.x * 4);
  f16x4 h = {(_Float16)v.x, (_Float16)v.y, (_Float16)v.z, (_Float16)v.w};
  *(f16x4*)(Wc + (size_t)n * DIM + threadIdx.x * 4) = h;
}

// ---------------- Projection GEMM: barrier-free, LDS-free ----------------
// 256 blocks x 128 thr (2 waves). Wave tile 32m x 256n, full K=1024, BK=32.
// B (Wc, 512 KB, L2-resident) loaded straight into MFMA B-frag registers,
// double-buffered. A loaded straight from x in A-frag layout (each instr:
// 16 rows x 64 B full cache lines, every byte used once), depth-4 ring.
// ZERO barriers -> no vmcnt(0) drains; compiler pipelines with vmcnt(N).
__global__ __launch_bounds__(128, 1) void proj_gemm(
    const float* __restrict__ x, const _Float16* __restrict__ Wc,
    _Float16* __restrict__ P) {
  const int tid = threadIdx.x;
  const int lane = tid & 63, wv = tid >> 6;
  const int fm = lane & 15, fq = lane >> 4;
  const int m0 = blockIdx.x * 64 + wv * 32;

  const float* gA0 = x + (size_t)(m0 + fm) * DIM + fq * 8;  // mi=0 rows
  const float* gA1 = gA0 + (size_t)16 * DIM;                // mi=1 rows
  const _Float16* gBb = Wc + (size_t)fm * DIM + fq * 8;

  f32x4 acc[2][16];
#pragma unroll
  for (int mi = 0; mi < 2; ++mi)
#pragma unroll
    for (int ni = 0; ni < 16; ++ni) acc[mi][ni] = (f32x4){0.f, 0.f, 0.f, 0.f};

  float4 xa[4][2][2];  // [ring slot][mi][half]
  f16x8 bf[2][16];     // [ring buf][ni]

#define LDA(slot, kt)                                          \
  {                                                            \
    xa[slot][0][0] = *(const float4*)(gA0 + (kt) * 32);        \
    xa[slot][0][1] = *(const float4*)(gA0 + (kt) * 32 + 4);    \
    xa[slot][1][0] = *(const float4*)(gA1 + (kt) * 32);        \
    xa[slot][1][1] = *(const float4*)(gA1 + (kt) * 32 + 4);    \
  }
#define LDB(buf, kt)                                                          \
  {                                                                           \
    _Pragma("unroll") for (int ni = 0; ni < 16; ++ni)                         \
        bf[buf][ni] = *(const f16x8*)(gBb + (size_t)(ni * 16) * DIM + (kt) * 32); \
  }

  LDA(0, 0); LDA(1, 1); LDA(2, 2); LDA(3, 3);
  LDB(0, 0); LDB(1, 1);

#pragma unroll
  for (int kt = 0; kt < 32; ++kt) {
    const int slot = kt & 3, buf = kt & 1;
    f16x8 af[2];
#pragma unroll
    for (int mi = 0; mi < 2; ++mi) {
      af[mi][0] = (_Float16)xa[slot][mi][0].x;
      af[mi][1] = (_Float16)xa[slot][mi][0].y;
      af[mi][2] = (_Float16)xa[slot][mi][0].z;
      af[mi][3] = (_Float16)xa[slot][mi][0].w;
      af[mi][4] = (_Float16)xa[slot][mi][1].x;
      af[mi][5] = (_Float16)xa[slot][mi][1].y;
      af[mi][6] = (_Float16)xa[slot][mi][1].z;
      af[mi][7] = (_Float16)xa[slot][mi][1].w;
    }
#pragma unroll
    for (int ni = 0; ni < 16; ++ni) {
      acc[0][ni] = __builtin_amdgcn_mfma_f32_16x16x32_f16(af[0], bf[buf][ni],
                                                          acc[0][ni], 0, 0, 0);
      acc[1][ni] = __builtin_amdgcn_mfma_f32_16x16x32_f16(af[1], bf[buf][ni],
                                                          acc[1][ni], 0, 0, 0);
    }
    if (kt + 4 < 32) LDA(slot, kt + 4);
    if (kt + 2 < 32) LDB(buf, kt + 2);
  }
#undef LDA
#undef LDB

  // C/D: col = lane&15 (n), row = (lane>>4)*4 + reg (m). v/ax cols interleaved:
  // P cols: [0..63]=k, [64..127]=q, [128..255]=v0,ax0,v1,ax1,...
#pragma unroll
  for (int mi = 0; mi < 2; ++mi)
#pragma unroll
    for (int ni = 0; ni < 16; ++ni) {
      const int gcol = ni * 16 + fm;
      const int pcol = gcol < 128 ? gcol
                     : (gcol < 192 ? 128 + 2 * (gcol - 128) : 129 + 2 * (gcol - 192));
#pragma unroll
      for (int r = 0; r < 4; ++r) {
        const int grow = m0 + mi * 16 + fq * 4 + r;
        P[(size_t)grow * 256 + pcol] = (_Float16)acc[mi][ni][r];
      }
    }
}

// ---------------- Sequential scan: barrier-free, LDS-free ----------------
// 128 blocks = (b, 16-row group), 256 thr = 16 rows x 16 lanes; thread owns
// S[b][r][4c..4c+3]. Per step: three INDEPENDENT 16-lane DPP all-reduces
// (S.k, S.q, k.q) run concurrently; h = al*(S.q) + cc*(k.q) so no reduce
// follows the state update. Inputs loaded per-thread straight from global
// through a depth-8 register ring (24 loads in flight, no barriers ever).
__device__ __forceinline__ float red16(float x) {
  int v = __builtin_amdgcn_update_dpp(0, __float_as_int(x), 0xB1, 0xF, 0xF, true);
  x += __int_as_float(v);
  v = __builtin_amdgcn_update_dpp(0, __float_as_int(x), 0x4E, 0xF, 0xF, true);
  x += __int_as_float(v);
  v = __builtin_amdgcn_update_dpp(0, __float_as_int(x), 0x124, 0xF, 0xF, true);
  x += __int_as_float(v);
  v = __builtin_amdgcn_update_dpp(0, __float_as_int(x), 0x128, 0xF, 0xF, true);
  x += __int_as_float(v);
  return x;
}

__global__ __launch_bounds__(256) void scan_kernel(
    const _Float16* __restrict__ P, const float* __restrict__ S0,
    const float* __restrict__ d_alpha, const float* __restrict__ b_alpha,
    float* __restrict__ out, float* __restrict__ Sout) {
  const int b = blockIdx.x >> 2;
  const int rg = blockIdx.x & 3;
  const int tid = threadIdx.x;
  const int c = tid & 15;
  const int r = rg * 16 + (tid >> 4);
  const int j0 = c * 4;

  float s[4];
  {
    float4 v = *(const float4*)(S0 + ((size_t)b * NST + r) * NST + j0);
    s[0] = v.x; s[1] = v.y; s[2] = v.z; s[3] = v.w;
  }
  const float da = d_alpha[r];
  const float ba = b_alpha[r];
  const float mda = -da * LOG2E;

  const _Float16* gp = P + (size_t)b * 256;  // step stride = 32*256 halves

  f16x4 kf[8], qf[8];
  f16x2 vaf[8];
#define LD_T(t)                                              \
  {                                                          \
    const _Float16* Pt = gp + (size_t)(t) * (BATCH * 256);   \
    kf[(t) & 7] = *(const f16x4*)(Pt + j0);                  \
    qf[(t) & 7] = *(const f16x4*)(Pt + 64 + j0);             \
    vaf[(t) & 7] = *(const f16x2*)(Pt + 128 + 2 * r);        \
  }

  LD_T(0); LD_T(1); LD_T(2); LD_T(3);
  LD_T(4); LD_T(5); LD_T(6); LD_T(7);

#pragma unroll 8
  for (int t = 0; t < T_STEPS; ++t) {
    const int p = t & 7;
    const float k0 = (float)kf[p][0], k1 = (float)kf[p][1];
    const float k2 = (float)kf[p][2], k3 = (float)kf[p][3];
    const float q0 = (float)qf[p][0], q1 = (float)qf[p][1];
    const float q2 = (float)qf[p][2], q3 = (float)qf[p][3];
    const float vi = (float)vaf[p][0];
    const float zcv = ((float)vaf[p][1] + ba) * (-LOG2E);  // off the rr chain
    if (t + 8 < T_STEPS) LD_T(t + 8);  // refill slot just consumed

    // three independent partial dots -> three concurrent 16-lane reduces
    float pa = fmaf(s[0], k0, s[1] * k1);
    float pb = fmaf(s[2], k2, s[3] * k3);
    float ua = fmaf(s[0], q0, s[1] * q1);
    float ub = fmaf(s[2], q2, s[3] * q3);
    float ka = fmaf(k0, q0, k1 * q1);
    float kb = fmaf(k2, q2, k3 * q3);
    const float rr = red16(pa + pb);
    const float uu = red16(ua + ub);
    const float kq = red16(ka + kb);

    // e = exp(-z) = 2^(rr*(-da*log2e) + (ax+ba)*(-log2e)); clamp |.| <= 45
    float tt = fmaf(rr, mda, zcv);
    tt = fminf(fmaxf(tt, -45.f), 45.f);
    const float e = exp2f(tt);
    const float al = __builtin_amdgcn_rcpf(1.f + e);  // sigmoid(z)
    const float cc = (e * vi) * al;                   // (1-al)*v

    s[0] = fmaf(al, s[0], cc * k0);
    s[1] = fmaf(al, s[1], cc * k1);
    s[2] = fmaf(al, s[2], cc * k2);
    s[3] = fmaf(al, s[3], cc * k3);

    const float h = fmaf(al, uu, cc * kq);  // = S_new . q (exact reorder)
    if (c == 0) {
      const float sg = __builtin_amdgcn_rcpf(1.f + __expf(-h));
      out[((size_t)t * BATCH + b) * NST + r] = h * h * sg;
    }
  }
#undef LD_T

  float4 o = {s[0], s[1], s[2], s[3]};
  *(float4*)(Sout + ((size_t)b * NST + r) * NST + j0) = o;
}

extern "C" void kernel_launch(void* const* d_in, const int* in_sizes, int n_in,
                              void* d_out, int out_size, void* d_ws, size_t ws_size,
                              hipStream_t stream) {
  const float* x  = (const float*)d_in[0];
  const float* S0 = (const float*)d_in[1];
  const float* Wk = (const float*)d_in[2];
  const float* Wv = (const float*)d_in[3];
  const float* Wq = (const float*)d_in[4];
  const float* Wa = (const float*)d_in[5];
  const float* da = (const float*)d_in[6];
  const float* ba = (const float*)d_in[7];

  float* out  = (float*)d_out;                        // [T,B,64]
  float* Sout = out + (size_t)T_STEPS * BATCH * NST;  // [B,64,64]
  _Float16* P = (_Float16*)d_ws;                      // [16384][256] f16 = 8 MB
  _Float16* Wc = (_Float16*)((char*)d_ws + (size_t)8 * 1024 * 1024);  // 512 KB

  wconv<<<256, 256, 0, stream>>>(Wk, Wv, Wq, Wa, Wc);
  proj_gemm<<<256, 128, 0, stream>>>(x, Wc, P);
  scan_kernel<<<4 * BATCH, 256, 0, stream>>>(P, S0, da, ba, out, Sout);
}

// Round 7
// 255.227 us; speedup vs baseline: 1.3259x; 1.3259x over previous
//
#include <hip/hip_runtime.h>
#include <hip/hip_bf16.h>

#define T_STEPS 512
#define BATCH 32
#define NST 64
#define DIM 1024
#define LOG2E 1.44269504f

typedef _Float16 f16x8 __attribute__((ext_vector_type(8)));
typedef _Float16 f16x4 __attribute__((ext_vector_type(4)));
typedef float f32x4 __attribute__((ext_vector_type(4)));

// ---------------- W concat + fp16 convert ----------------
// Wc[256][1024] fp16, row order [Wk | Wq | Wv | Wa].
__global__ __launch_bounds__(256) void wconv(
    const float* __restrict__ Wk, const float* __restrict__ Wv,
    const float* __restrict__ Wq, const float* __restrict__ Wa,
    _Float16* __restrict__ Wc) {
  const int n = blockIdx.x;
  const int g = n >> 6, r = n & 63;
  const float* W = (g == 0) ? Wk : (g == 1) ? Wq : (g == 2) ? Wv : Wa;
  float4 v = *(const float4*)(W + (size_t)r * DIM + threadIdx.x * 4);
  f16x4 h = {(_Float16)v.x, (_Float16)v.y, (_Float16)v.z, (_Float16)v.w};
  *(f16x4*)(Wc + (size_t)n * DIM + threadIdx.x * 4) = h;
}

// ---------------- Projection GEMM: barrier-free, LDS-free, right-sized ----
// 256 blocks x 512 thr (8 waves/CU). Wave tile 32m x 64n (one gate per wave:
// wn=wv&3), full K=1024, BK=32, depth-2 register double-buffer.
// acc 2x4 frags = 32 VGPR; A buf 2x16 f32 = 32; B buf 2x4 f16x8 = 32. ~120 tot.
// ZERO barriers/LDS -> no vmcnt(0) drains; 8 waves/CU hide HBM/L2 latency.
__global__ __launch_bounds__(512, 2) void proj_gemm(
    const float* __restrict__ x, const _Float16* __restrict__ Wc,
    _Float16* __restrict__ P) {
  const int tid = threadIdx.x;
  const int lane = tid & 63, wv = tid >> 6;
  const int wm = wv >> 2, wn = wv & 3;
  const int fm = lane & 15, fq = lane >> 4;
  const int m0 = blockIdx.x * 64 + wm * 32;

  const float* gA0 = x + (size_t)(m0 + fm) * DIM + fq * 8;   // mi=0 rows
  const float* gA1 = gA0 + (size_t)16 * DIM;                 // mi=1 rows
  const _Float16* gB = Wc + (size_t)(wn * 64 + fm) * DIM + fq * 8;

  f32x4 acc[2][4];
#pragma unroll
  for (int mi = 0; mi < 2; ++mi)
#pragma unroll
    for (int ni = 0; ni < 4; ++ni) acc[mi][ni] = (f32x4){0.f, 0.f, 0.f, 0.f};

  float4 xa[2][2][2];  // [buf][mi][half]
  f16x8 bf[2][4];      // [buf][ni]

#define LDA(buf, kt)                                           \
  {                                                            \
    xa[buf][0][0] = *(const float4*)(gA0 + (kt) * 32);         \
    xa[buf][0][1] = *(const float4*)(gA0 + (kt) * 32 + 4);     \
    xa[buf][1][0] = *(const float4*)(gA1 + (kt) * 32);         \
    xa[buf][1][1] = *(const float4*)(gA1 + (kt) * 32 + 4);     \
  }
#define LDB(buf, kt)                                                           \
  {                                                                            \
    _Pragma("unroll") for (int ni = 0; ni < 4; ++ni)                           \
        bf[buf][ni] = *(const f16x8*)(gB + (size_t)(ni * 16) * DIM + (kt) * 32); \
  }

  LDA(0, 0); LDB(0, 0);
  LDA(1, 1); LDB(1, 1);

#pragma unroll 4
  for (int kt = 0; kt < 32; ++kt) {
    const int buf = kt & 1;
    f16x8 af[2];
#pragma unroll
    for (int mi = 0; mi < 2; ++mi) {
      af[mi][0] = (_Float16)xa[buf][mi][0].x;
      af[mi][1] = (_Float16)xa[buf][mi][0].y;
      af[mi][2] = (_Float16)xa[buf][mi][0].z;
      af[mi][3] = (_Float16)xa[buf][mi][0].w;
      af[mi][4] = (_Float16)xa[buf][mi][1].x;
      af[mi][5] = (_Float16)xa[buf][mi][1].y;
      af[mi][6] = (_Float16)xa[buf][mi][1].z;
      af[mi][7] = (_Float16)xa[buf][mi][1].w;
    }
#pragma unroll
    for (int ni = 0; ni < 4; ++ni) {
      acc[0][ni] = __builtin_amdgcn_mfma_f32_16x16x32_f16(af[0], bf[buf][ni],
                                                          acc[0][ni], 0, 0, 0);
      acc[1][ni] = __builtin_amdgcn_mfma_f32_16x16x32_f16(af[1], bf[buf][ni],
                                                          acc[1][ni], 0, 0, 0);
    }
    if (kt + 2 < 32) { LDA(buf, kt + 2); LDB(buf, kt + 2); }
  }
#undef LDA
#undef LDB

  // C/D: col = lane&15 (n), row = (lane>>4)*4 + reg (m).
  // P cols: [0..63]=k (wn0), [64..127]=q (wn1), [128..255]= v,ax interleaved.
#pragma unroll
  for (int mi = 0; mi < 2; ++mi)
#pragma unroll
    for (int ni = 0; ni < 4; ++ni) {
      const int gcol = wn * 64 + ni * 16 + fm;
      const int pcol = gcol < 128 ? gcol
                     : (gcol < 192 ? 128 + 2 * (gcol - 128) : 129 + 2 * (gcol - 192));
#pragma unroll
      for (int r = 0; r < 4; ++r) {
        const int grow = m0 + mi * 16 + fq * 4 + r;
        P[(size_t)grow * 256 + pcol] = (_Float16)acc[mi][ni][r];
      }
    }
}

// ---------------- Sequential scan ----------------
// 128 blocks = (b, 16-row group), 256 thr = 16 rows x 16 lanes; thread owns
// S[b][r][4c..4c+3]. lbuf f32, staged 16 B/lane (conflict-free, R4-verified
// pattern) with f16->f32 cvt at staging time -> zero converts in-loop.
// Three INDEPENDENT 16-lane DPP reduces/step; h = al*uu + cc*kq.
// Chunk global loads issued at si==1 (mid-chunk) so they drain ~2000 cyc
// before the boundary barrier's vmcnt(0).
__device__ __forceinline__ float red16(float x) {
  int v = __builtin_amdgcn_update_dpp(0, __float_as_int(x), 0xB1, 0xF, 0xF, true);
  x += __int_as_float(v);
  v = __builtin_amdgcn_update_dpp(0, __float_as_int(x), 0x4E, 0xF, 0xF, true);
  x += __int_as_float(v);
  v = __builtin_amdgcn_update_dpp(0, __float_as_int(x), 0x124, 0xF, 0xF, true);
  x += __int_as_float(v);
  v = __builtin_amdgcn_update_dpp(0, __float_as_int(x), 0x128, 0xF, 0xF, true);
  x += __int_as_float(v);
  return x;
}

__global__ __launch_bounds__(256) void scan_kernel(
    const _Float16* __restrict__ P, const float* __restrict__ S0,
    const float* __restrict__ d_alpha, const float* __restrict__ b_alpha,
    float* __restrict__ out, float* __restrict__ Sout) {
  const int b = blockIdx.x >> 2;
  const int rg = blockIdx.x & 3;
  const int tid = threadIdx.x;
  const int c = tid & 15;
  const int r = rg * 16 + (tid >> 4);
  const int j0 = c * 4;

  __shared__ __align__(16) float lbuf[2 * 2048];  // 2 chunks x 8 steps x 256 f32

  float s[4];
  {
    float4 v = *(const float4*)(S0 + ((size_t)b * NST + r) * NST + j0);
    s[0] = v.x; s[1] = v.y; s[2] = v.z; s[3] = v.w;
  }
  const float da = d_alpha[r];
  const float ba = b_alpha[r];
  const float mda = -da * LOG2E;

  // staging: thread covers steps {tid>>6, (tid>>6)+4} at cols (tid&63)*4
  const int sstep = tid >> 6;
  const int scol = (tid & 63) * 4;

  f16x4 rA[2];
#define GLD(ch)                                                                 \
  {                                                                             \
    rA[0] = *(const f16x4*)(P + ((size_t)(((ch)*8 + sstep) * BATCH + b)) * 256 + scol); \
    rA[1] = *(const f16x4*)(P + ((size_t)(((ch)*8 + sstep + 4) * BATCH + b)) * 256 + scol); \
  }
#define CVWR(slot)                                                    \
  {                                                                   \
    float4 w0 = {(float)rA[0][0], (float)rA[0][1], (float)rA[0][2],   \
                 (float)rA[0][3]};                                    \
    float4 w1 = {(float)rA[1][0], (float)rA[1][1], (float)rA[1][2],   \
                 (float)rA[1][3]};                                    \
    *(float4*)(lbuf + (slot)*2048 + sstep * 256 + scol) = w0;         \
    *(float4*)(lbuf + (slot)*2048 + (sstep + 4) * 256 + scol) = w1;   \
  }

  GLD(0); CVWR(0);
  GLD(1); CVWR(1);
  __syncthreads();

  float4 kf[2], qf[2];
  float2 va[2];
#define PREF(tn)                                                             \
  {                                                                          \
    const int pp = (tn) & 1;                                                 \
    const float* Pn = lbuf + (((tn) >> 3) & 1) * 2048 + ((tn) & 7) * 256;    \
    kf[pp] = *(const float4*)(Pn + j0);                                      \
    qf[pp] = *(const float4*)(Pn + 64 + j0);                                 \
    va[pp] = *(const float2*)(Pn + 128 + 2 * r);                             \
  }

  PREF(0);
  PREF(1);
  for (int ch = 0; ch < 64; ++ch) {
#pragma unroll
    for (int si = 0; si < 8; ++si) {
      const int t = ch * 8 + si;
      const int p = t & 1;

      const float k0 = kf[p].x, k1 = kf[p].y, k2 = kf[p].z, k3 = kf[p].w;
      const float q0 = qf[p].x, q1 = qf[p].y, q2 = qf[p].z, q3 = qf[p].w;
      const float vi = va[p].x;
      const float zcv = (va[p].y + ba) * (-LOG2E);  // off the rr chain
      if (t + 2 < T_STEPS) PREF(t + 2);
      if (si == 1 && ch + 2 < 64) GLD(ch + 2);  // drains well before barrier

      // three independent partial dots -> three concurrent 16-lane reduces
      float pa = fmaf(s[0], k0, s[1] * k1);
      float pb = fmaf(s[2], k2, s[3] * k3);
      float ua = fmaf(s[0], q0, s[1] * q1);
      float ub = fmaf(s[2], q2, s[3] * q3);
      float ka = fmaf(k0, q0, k1 * q1);
      float kb = fmaf(k2, q2, k3 * q3);
      const float rr = red16(pa + pb);
      const float uu = red16(ua + ub);
      const float kq = red16(ka + kb);

      // e = exp(-z) = 2^(rr*(-da*log2e) + (ax+ba)*(-log2e)); clamp |.| <= 45
      float tt = fmaf(rr, mda, zcv);
      tt = fminf(fmaxf(tt, -45.f), 45.f);
      const float e = exp2f(tt);
      const float al = __builtin_amdgcn_rcpf(1.f + e);  // sigmoid(z)
      const float cc = (e * vi) * al;                   // (1-al)*v

      s[0] = fmaf(al, s[0], cc * k0);
      s[1] = fmaf(al, s[1], cc * k1);
      s[2] = fmaf(al, s[2], cc * k2);
      s[3] = fmaf(al, s[3], cc * k3);

      const float h = fmaf(al, uu, cc * kq);  // = S_new . q (exact reorder)
      if (c == 0) {
        const float sg = __builtin_amdgcn_rcpf(1.f + __expf(-h));
        out[((size_t)t * BATCH + b) * NST + r] = h * h * sg;
      }
    }
    if (ch + 2 < 64) {
      __syncthreads();   // reads of chunk ch (slot ch&1) done
      CVWR(ch & 1);      // store chunk ch+2 (loaded at si==1 above)
      __syncthreads();   // visible before chunk ch+2 read
    }
  }
#undef PREF
#undef GLD
#undef CVWR

  float4 o = {s[0], s[1], s[2], s[3]};
  *(float4*)(Sout + ((size_t)b * NST + r) * NST + j0) = o;
}

extern "C" void kernel_launch(void* const* d_in, const int* in_sizes, int n_in,
                              void* d_out, int out_size, void* d_ws, size_t ws_size,
                              hipStream_t stream) {
  const float* x  = (const float*)d_in[0];
  const float* S0 = (const float*)d_in[1];
  const float* Wk = (const float*)d_in[2];
  const float* Wv = (const float*)d_in[3];
  const float* Wq = (const float*)d_in[4];
  const float* Wa = (const float*)d_in[5];
  const float* da = (const float*)d_in[6];
  const float* ba = (const float*)d_in[7];

  float* out  = (float*)d_out;                        // [T,B,64]
  float* Sout = out + (size_t)T_STEPS * BATCH * NST;  // [B,64,64]
  _Float16* P = (_Float16*)d_ws;                      // [16384][256] f16 = 8 MB
  _Float16* Wc = (_Float16*)((char*)d_ws + (size_t)8 * 1024 * 1024);  // 512 KB

  wconv<<<256, 256, 0, stream>>>(Wk, Wv, Wq, Wa, Wc);
  proj_gemm<<<256, 512, 0, stream>>>(x, Wc, P);
  scan_kernel<<<4 * BATCH, 256, 0, stream>>>(P, S0, da, ba, out, Sout);
}